// Round 1
// baseline (418.346 us; speedup 1.0000x reference)
//
#include <hip/hip_runtime.h>

// CrossNet: B=500000 rows, D=128, L=4.
//   x0 = inputs; xl = x0
//   for i in 0..L-1: s = dot(xl, w_i); xl = x0 * s + b_i + xl
// Memory-bound streaming: 512B read + 512B write per row, ~2KFLOP per row.
// Layout: 32 lanes per row, one float4 per lane (16B/lane coalescing sweet
// spot). Dot product via 5-step shfl_xor butterfly within the 32-lane half
// of the wave64 (xor masks <=16 never cross the 32-lane boundary).
// Weights/biases (4KB unique, L2-resident) preloaded once per thread,
// amortized over a grid-stride loop.

#define CN_D 128
#define CN_L 4

__global__ __launch_bounds__(256) void crossnet_kernel(
    const float* __restrict__ inputs,
    const float* __restrict__ kernels,
    const float* __restrict__ biases,
    float* __restrict__ out,
    int nrows)
{
    const int lane = threadIdx.x & 31;        // float4 index within row
    const int row_in_blk = threadIdx.x >> 5;  // 0..7
    const int rows_per_blk = blockDim.x >> 5; // 8

    // Preload per-lane weight/bias fragments for all 4 layers (L2 broadcast).
    float4 w4[CN_L], b4[CN_L];
#pragma unroll
    for (int i = 0; i < CN_L; ++i) {
        w4[i] = ((const float4*)(kernels + i * CN_D))[lane];
        b4[i] = ((const float4*)(biases + i * CN_D))[lane];
    }

    for (long long row = (long long)blockIdx.x * rows_per_blk + row_in_blk;
         row < nrows;
         row += (long long)gridDim.x * rows_per_blk)
    {
        const float4* xp = (const float4*)(inputs + row * CN_D);
        float4 x = xp[lane];
        float4 xl = x;

#pragma unroll
        for (int i = 0; i < CN_L; ++i) {
            // Partial dot over this lane's 4 elements.
            float p = xl.x * w4[i].x + xl.y * w4[i].y
                    + xl.z * w4[i].z + xl.w * w4[i].w;
            // Butterfly reduce across the 32 lanes owning this row.
            p += __shfl_xor(p, 1);
            p += __shfl_xor(p, 2);
            p += __shfl_xor(p, 4);
            p += __shfl_xor(p, 8);
            p += __shfl_xor(p, 16);
            // xl = x0 * s + b + xl
            xl.x = fmaf(x.x, p, xl.x + b4[i].x);
            xl.y = fmaf(x.y, p, xl.y + b4[i].y);
            xl.z = fmaf(x.z, p, xl.z + b4[i].z);
            xl.w = fmaf(x.w, p, xl.w + b4[i].w);
        }

        float4* op = (float4*)(out + row * CN_D);
        op[lane] = xl;
    }
}

extern "C" void kernel_launch(void* const* d_in, const int* in_sizes, int n_in,
                              void* d_out, int out_size, void* d_ws, size_t ws_size,
                              hipStream_t stream) {
    const float* inputs  = (const float*)d_in[0];
    const float* kernels = (const float*)d_in[1];
    const float* biases  = (const float*)d_in[2];
    float* out = (float*)d_out;

    const int nrows = in_sizes[0] / CN_D;  // 500000

    const int block = 256;                 // 8 rows per block
    const int grid  = 4096;                // grid-stride; ~15 iters/block

    crossnet_kernel<<<grid, block, 0, stream>>>(inputs, kernels, biases, out, nrows);
}